// Round 3
// baseline (2375.250 us; speedup 1.0000x reference)
//
#include <hip/hip_runtime.h>
#include <hip/hip_cooperative_groups.h>
#include <cmath>

namespace cg = cooperative_groups;

#define N_TOT 30000
#define N0_   18000
#define R_    5
#define E_    600000
#define RN    (R_ * N_TOT)
#define NC_   (N_TOT * 8)        // logits elements
#define NX_   (N_TOT * 128)      // x elements
#define GRID_C 1024
#define NTHR   (GRID_C * 256)
#define CH_    147               // ceil(RN / GRID_C)

// ---------------------------------------------------------------------------
// Fused MLP, 8 nodes per 128-thread block (unchanged from R2).
// ---------------------------------------------------------------------------
__global__ __launch_bounds__(128) void mlp_kernel(
    const float* __restrict__ feat0, const float* __restrict__ feat1,
    const float* __restrict__ W0, const float* __restrict__ b0,
    const float* __restrict__ W1, const float* __restrict__ b1,
    const float* __restrict__ Wm1, const float* __restrict__ bm1,
    const float* __restrict__ Wm2, const float* __restrict__ bm2,
    float* __restrict__ xout)
{
    const int j = threadIdx.x;
    const int lane = j & 63, wv_id = j >> 6;
    const int row0 = blockIdx.x * 8;

    __shared__ float sh[8][128];
    __shared__ float red[2][8];

    const bool is0 = (row0 < N0_);
    const float* __restrict__ fbase =
        is0 ? feat0 + (size_t)row0 * 256 : feat1 + (size_t)(row0 - N0_) * 128;
    const float* __restrict__ W = is0 ? W0 : W1;
    const int K = is0 ? 256 : 128;
    const float bias = is0 ? b0[j] : b1[j];

    float acc[8];
    #pragma unroll
    for (int p = 0; p < 8; ++p) acc[p] = bias;

    for (int k = 0; k < K; k += 4) {
        float w0 = W[(k + 0) * 128 + j];
        float w1 = W[(k + 1) * 128 + j];
        float w2 = W[(k + 2) * 128 + j];
        float w3 = W[(k + 3) * 128 + j];
        #pragma unroll
        for (int p = 0; p < 8; ++p) {
            const float4 f4 = *(const float4*)(fbase + (size_t)p * K + k);
            acc[p] = fmaf(f4.x, w0, acc[p]);
            acc[p] = fmaf(f4.y, w1, acc[p]);
            acc[p] = fmaf(f4.z, w2, acc[p]);
            acc[p] = fmaf(f4.w, w3, acc[p]);
        }
    }
    #pragma unroll
    for (int p = 0; p < 8; ++p) sh[p][j] = acc[p];
    __syncthreads();

    float t1[8];
    #pragma unroll
    for (int p = 0; p < 8; ++p) t1[p] = bm1[j];
    for (int k = 0; k < 128; k += 4) {
        float w0 = Wm1[(k + 0) * 128 + j];
        float w1 = Wm1[(k + 1) * 128 + j];
        float w2 = Wm1[(k + 2) * 128 + j];
        float w3 = Wm1[(k + 3) * 128 + j];
        #pragma unroll
        for (int p = 0; p < 8; ++p) {
            const float4 f4 = *(const float4*)(&sh[p][k]);
            t1[p] = fmaf(f4.x, w0, t1[p]);
            t1[p] = fmaf(f4.y, w1, t1[p]);
            t1[p] = fmaf(f4.z, w2, t1[p]);
            t1[p] = fmaf(f4.w, w3, t1[p]);
        }
    }

    float mean[8];
    {
        #pragma unroll
        for (int p = 0; p < 8; ++p) {
            float s = t1[p];
            for (int o = 32; o > 0; o >>= 1) s += __shfl_down(s, o, 64);
            if (lane == 0) red[wv_id][p] = s;
        }
        __syncthreads();
        #pragma unroll
        for (int p = 0; p < 8; ++p) mean[p] = (red[0][p] + red[1][p]) * (1.0f / 128.0f);
        __syncthreads();
        #pragma unroll
        for (int p = 0; p < 8; ++p) {
            float d = t1[p] - mean[p];
            float s = d * d;
            for (int o = 32; o > 0; o >>= 1) s += __shfl_down(s, o, 64);
            if (lane == 0) red[wv_id][p] = s;
        }
        __syncthreads();
    }
    #pragma unroll
    for (int p = 0; p < 8; ++p) {
        float var = (red[0][p] + red[1][p]) * (1.0f / 128.0f);
        float z = fmaxf((t1[p] - mean[p]) / sqrtf(var + 1e-5f), 0.0f);
        t1[p] = z;
    }
    __syncthreads();
    #pragma unroll
    for (int p = 0; p < 8; ++p) sh[p][j] = t1[p];
    __syncthreads();

    float t2[8];
    #pragma unroll
    for (int p = 0; p < 8; ++p) t2[p] = bm2[j];
    for (int k = 0; k < 128; k += 4) {
        float w0 = Wm2[(k + 0) * 128 + j];
        float w1 = Wm2[(k + 1) * 128 + j];
        float w2 = Wm2[(k + 2) * 128 + j];
        float w3 = Wm2[(k + 3) * 128 + j];
        #pragma unroll
        for (int p = 0; p < 8; ++p) {
            const float4 f4 = *(const float4*)(&sh[p][k]);
            t2[p] = fmaf(f4.x, w0, t2[p]);
            t2[p] = fmaf(f4.y, w1, t2[p]);
            t2[p] = fmaf(f4.z, w2, t2[p]);
            t2[p] = fmaf(f4.w, w3, t2[p]);
        }
    }

    float mu[8];
    {
        #pragma unroll
        for (int p = 0; p < 8; ++p) {
            float s = t2[p];
            for (int o = 32; o > 0; o >>= 1) s += __shfl_down(s, o, 64);
            if (lane == 0) red[wv_id][p] = s;
        }
        __syncthreads();
        #pragma unroll
        for (int p = 0; p < 8; ++p) mu[p] = (red[0][p] + red[1][p]) * (1.0f / 128.0f);
        __syncthreads();
        #pragma unroll
        for (int p = 0; p < 8; ++p) {
            float d = t2[p] - mu[p];
            float s = d * d;
            for (int o = 32; o > 0; o >>= 1) s += __shfl_down(s, o, 64);
            if (lane == 0) red[wv_id][p] = s;
        }
        __syncthreads();
    }
    #pragma unroll
    for (int p = 0; p < 8; ++p) {
        float sd = sqrtf((red[0][p] + red[1][p]) * (1.0f / 127.0f));
        float r = (t2[p] - mu[p]) / sd;
        if (!(fabsf(r) <= 3.402823466e38f)) {
            r = (r != r) ? 0.0f : ((r > 0.0f) ? 3.402823466e38f : -3.402823466e38f);
        }
        xout[(size_t)(row0 + p) * 128 + j] = r;
    }
}

// ---------------------------------------------------------------------------
// Cooperative kernel: preprocessing + 8-iteration outer loop with device-side
// early break. 1024 blocks x 256 threads, co-resident (launch_bounds 256,4).
// ---------------------------------------------------------------------------
__global__ __launch_bounds__(256, 4) void coop_kernel(
    const int* __restrict__ src, const int* __restrict__ dst,
    const int* __restrict__ rel,
    float* __restrict__ xbuf, float* __restrict__ xalt,
    int* __restrict__ deg_i, float* __restrict__ dinv,
    int* __restrict__ rp, int* __restrict__ fill,
    int* __restrict__ csr_dst, float* __restrict__ csr_w,
    float* __restrict__ csr_edinv,
    int* __restrict__ part, int* __restrict__ poff,
    float* __restrict__ accbuf, float* __restrict__ ug,
    float* __restrict__ c_l1, int* __restrict__ act,
    float** __restrict__ cur_slot)
{
    cg::grid_group grid = cg::this_grid();
    const int tid = threadIdx.x;
    const int gtid = blockIdx.x * 256 + tid;
    const int lane = tid & 63;
    const int wv = tid >> 6;

    __shared__ int s_int[4];
    __shared__ float sacc[4][10];

    // ---- P0: zero state ----------------------------------------------
    for (int i = gtid; i < RN; i += NTHR) { deg_i[i] = 0; fill[i] = 0; }
    if (gtid < 5) ug[gtid] = 0.2f;
    if (gtid == 0) { act[0] = 1; rp[RN] = E_; }
    if (gtid < 128) accbuf[gtid] = 0.0f;
    grid.sync();

    // ---- P1: degree histogram ----------------------------------------
    for (int e = gtid; e < E_; e += NTHR)
        atomicAdd(&deg_i[rel[e] * N_TOT + src[e]], 1);
    grid.sync();

    // ---- P2: dinv + per-block chunk sums -----------------------------
    for (int i = gtid; i < RN; i += NTHR) {
        int dg = deg_i[i];
        dinv[i] = (dg > 0) ? 1.0f / sqrtf((float)dg) : 0.0f;
    }
    {
        const int b = blockIdx.x;
        const int i = b * CH_ + tid;
        int v = (tid < CH_ && i < RN) ? deg_i[i] : 0;
        int s = v;
        for (int o = 32; o > 0; o >>= 1) s += __shfl_down(s, o, 64);
        if (lane == 0) s_int[wv] = s;
        __syncthreads();
        if (tid == 0) part[b] = s_int[0] + s_int[1] + s_int[2] + s_int[3];
    }
    grid.sync();

    // ---- P3: block0 scans part[1024] -> poff -------------------------
    if (blockIdx.x == 0) {
        int v[4]; int s = 0;
        #pragma unroll
        for (int j = 0; j < 4; ++j) { v[j] = part[tid * 4 + j]; s += v[j]; }
        int sc = s;
        for (int o = 1; o < 64; o <<= 1) { int t2 = __shfl_up(sc, o, 64); if (lane >= o) sc += t2; }
        if (lane == 63) s_int[wv] = sc;
        __syncthreads();
        int woff = 0;
        for (int i = 0; i < wv; ++i) woff += s_int[i];
        int run = woff + sc - s;
        #pragma unroll
        for (int j = 0; j < 4; ++j) { poff[tid * 4 + j] = run; run += v[j]; }
    }
    grid.sync();

    // ---- P4: per-chunk exclusive scan -> rp --------------------------
    {
        const int b = blockIdx.x;
        const int i = b * CH_ + tid;
        int v = (tid < CH_ && i < RN) ? deg_i[i] : 0;
        int sc = v;
        for (int o = 1; o < 64; o <<= 1) { int t2 = __shfl_up(sc, o, 64); if (lane >= o) sc += t2; }
        if (lane == 63) s_int[wv] = sc;
        __syncthreads();
        int woff = 0;
        for (int j = 0; j < wv; ++j) woff += s_int[j];
        int excl = woff + sc - v;
        if (tid < CH_ && i < RN) rp[i] = poff[b] + excl;
    }
    grid.sync();

    // ---- P5: counting-sort scatter into CSR --------------------------
    for (int e = gtid; e < E_; e += NTHR) {
        int s = src[e], r = rel[e], d = dst[e];
        int key = r * N_TOT + s;
        int pos = rp[key] + atomicAdd(&fill[key], 1);
        csr_dst[pos] = d;
        csr_w[pos] = 1.0f / (float)deg_i[key];
        csr_edinv[pos] = dinv[key] * dinv[r * N_TOT + d];
    }
    __threadfence();
    grid.sync();

    // ---- outer loop ---------------------------------------------------
    float* xa = xbuf;
    float* xb = xalt;
    const int wid = blockIdx.x * 4 + wv;
    const int nw = GRID_C * 4;

    for (int k = 0; k < 8; ++k) {
        // tv phase (act[k] is always 1 when reached; break handles the rest)
        float na[5] = {0, 0, 0, 0, 0};
        float ea[5] = {0, 0, 0, 0, 0};
        for (int n = wid; n < N_TOT; n += nw) {
            const float2 xs = ((const float2*)(xa + (size_t)n * 128))[lane];
            const float pp = fmaf(xs.x, xs.x, xs.y * xs.y);
            #pragma unroll
            for (int r = 0; r < 5; ++r) {
                const int e0 = rp[r * N_TOT + n];
                const int e1 = rp[r * N_TOT + n + 1];
                if (e1 > e0) na[r] += pp;
                float acc = 0.0f;
                for (int e = e0; e < e1; ++e) {
                    const int dn = csr_dst[e];
                    const float2 xd = ((const float2*)(xa + (size_t)dn * 128))[lane];
                    acc = fmaf(csr_edinv[e], fmaf(xs.x, xd.x, xs.y * xd.y), acc);
                }
                ea[r] += acc;
            }
        }
        #pragma unroll
        for (int r = 0; r < 5; ++r) {
            float a = na[r], b2 = ea[r];
            for (int o = 32; o > 0; o >>= 1) {
                a += __shfl_down(a, o, 64);
                b2 += __shfl_down(b2, o, 64);
            }
            if (lane == 0) { sacc[wv][r] = a; sacc[wv][5 + r] = b2; }
        }
        __syncthreads();
        if (tid < 10)
            atomicAdd(&accbuf[k * 16 + tid],
                      sacc[0][tid] + sacc[1][tid] + sacc[2][tid] + sacc[3][tid]);
        __threadfence();
        grid.sync();

        // scalar phase: mirror descent, lanes 0..7 of block 0
        if (blockIdx.x == 0 && tid < 8) {
            const int r = tid;
            float w = (r < 5) ? (accbuf[k * 16 + r] - accbuf[k * 16 + 5 + r]) * (1.0f / 30000.0f)
                              : 0.0f;
            float l1 = fabsf(w);
            for (int o = 4; o > 0; o >>= 1) l1 += __shfl_xor(l1, o, 8);
            if (k == 0 && r == 0) c_l1[0] = l1;
            float u = (r < 5) ? ug[r] : 0.0f;
            const float fi = l1 + 3.0f;
            bool mact = true;
            for (int t = 1; t <= 20; ++t) {
                float T = sqrtf(3.2188758248682006f / ((float)t * fi * fi));
                float ta = u * expf(-T * (3.0f * u + w));
                float ssum = ta;
                for (int o = 4; o > 0; o >>= 1) ssum += __shfl_xor(ssum, o, 8);
                float un = ta / ssum;
                float d0 = u - un;
                float dq = d0 * d0;
                for (int o = 4; o > 0; o >>= 1) dq += __shfl_xor(dq, o, 8);
                if (mact) u = un;
                mact = mact && (sqrtf(dq) >= 1e-3f);
            }
            if (r < 5) ug[r] = u;
            if (r == 0) act[k + 1] = (l1 / c_l1[0] >= 0.3f) ? 1 : 0;
        }
        __threadfence();
        grid.sync();

        if (act[k + 1] == 0) break;

        // msg + update phase: xb = xa/21 + (20/21) * msg(xa)
        {
            const float u0 = ug[0], u1 = ug[1], u2 = ug[2], u3 = ug[3], u4 = ug[4];
            for (int n = wid; n < N_TOT; n += nw) {
                const float2 xs = ((const float2*)(xa + (size_t)n * 128))[lane];
                float ax = 0.0f, ay = 0.0f;
                #pragma unroll
                for (int r = 0; r < 5; ++r) {
                    const float ur = (r == 0) ? u0 : (r == 1) ? u1 : (r == 2) ? u2 : (r == 3) ? u3 : u4;
                    const int e0 = rp[r * N_TOT + n];
                    const int e1 = rp[r * N_TOT + n + 1];
                    for (int e = e0; e < e1; ++e) {
                        const float wgt = ur * csr_w[e];
                        const int dn = csr_dst[e];
                        const float2 xd = ((const float2*)(xa + (size_t)dn * 128))[lane];
                        ax = fmaf(wgt, xd.x, ax);
                        ay = fmaf(wgt, xd.y, ay);
                    }
                }
                const float ci = 1.0f / 21.0f, cb = 20.0f / 21.0f;
                ((float2*)(xb + (size_t)n * 128))[lane] =
                    make_float2(fmaf(cb, ax, xs.x * ci), fmaf(cb, ay, xs.y * ci));
            }
        }
        { float* t = xa; xa = xb; xb = t; }
        __threadfence();
        grid.sync();
    }

    if (blockIdx.x == 0 && tid == 0) *cur_slot = xa;
}

// ---------------------------------------------------------------------------
// epilogue: logits = x@Wout + bout ; write logits, x, u
// ---------------------------------------------------------------------------
__global__ __launch_bounds__(256) void final_kernel(float* const* __restrict__ cur_slot,
                                                    const float* __restrict__ Wout,
                                                    const float* __restrict__ bout,
                                                    const float* __restrict__ ug,
                                                    float* __restrict__ out)
{
    const float* __restrict__ x = cur_slot[0];
    const int nl = threadIdx.x >> 7;
    const int n = blockIdx.x * 2 + nl;
    const int j = threadIdx.x & 127;
    const int lane = threadIdx.x & 63;
    const int wv = threadIdx.x >> 6;
    float xv = x[(size_t)n * 128 + j];
    out[(size_t)NC_ + (size_t)n * 128 + j] = xv;
    float p[8];
    #pragma unroll
    for (int c = 0; c < 8; ++c) p[c] = xv * Wout[j * 8 + c];
    #pragma unroll
    for (int c = 0; c < 8; ++c)
        for (int o = 32; o > 0; o >>= 1) p[c] += __shfl_down(p[c], o, 64);
    __shared__ float sp[4][8];
    if (lane == 0) {
        #pragma unroll
        for (int c = 0; c < 8; ++c) sp[wv][c] = p[c];
    }
    __syncthreads();
    if (j < 8) {
        int c = j;
        out[(size_t)n * 8 + c] = bout[c] + sp[2 * nl][c] + sp[2 * nl + 1][c];
    }
    if (blockIdx.x == 0 && threadIdx.x < 5)
        out[(size_t)NC_ + (size_t)NX_ + threadIdx.x] = ug[threadIdx.x];
}

// ---------------------------------------------------------------------------
extern "C" void kernel_launch(void* const* d_in, const int* in_sizes, int n_in,
                              void* d_out, int out_size, void* d_ws, size_t ws_size,
                              hipStream_t stream)
{
    const float* feat0 = (const float*)d_in[0];
    const float* feat1 = (const float*)d_in[1];
    const float* W0   = (const float*)d_in[2];
    const float* b0   = (const float*)d_in[3];
    const float* W1   = (const float*)d_in[4];
    const float* b1   = (const float*)d_in[5];
    const float* Wm1  = (const float*)d_in[6];
    const float* bm1  = (const float*)d_in[7];
    const float* Wm2  = (const float*)d_in[8];
    const float* bm2  = (const float*)d_in[9];
    const float* Wout = (const float*)d_in[10];
    const float* bout = (const float*)d_in[11];
    const int* src = (const int*)d_in[12];
    const int* dst = (const int*)d_in[13];
    const int* rel = (const int*)d_in[14];
    float* out = (float*)d_out;

    char* p = (char*)d_ws;
    auto alloc = [&](size_t bytes) { char* q = p; p += (bytes + 255) & ~(size_t)255; return q; };
    float* xbuf      = (float*)alloc((size_t)NX_ * 4);
    float* xalt      = (float*)alloc((size_t)NX_ * 4);
    int*   deg_i     = (int*)  alloc((size_t)RN * 4);
    float* dinv      = (float*)alloc((size_t)RN * 4);
    int*   rp        = (int*)  alloc(((size_t)RN + 1) * 4);
    int*   fill      = (int*)  alloc((size_t)RN * 4);
    int*   csr_dst   = (int*)  alloc((size_t)E_ * 4);
    float* csr_w     = (float*)alloc((size_t)E_ * 4);
    float* csr_edinv = (float*)alloc((size_t)E_ * 4);
    int*   part      = (int*)  alloc((size_t)GRID_C * 4);
    int*   poff      = (int*)  alloc((size_t)GRID_C * 4);
    float* accbuf    = (float*)alloc(128 * 4);
    float* ug        = (float*)alloc(64);
    float* c_l1      = (float*)alloc(64);
    int*   act       = (int*)  alloc(64);
    float** cur_slot = (float**)alloc(64);

    mlp_kernel<<<N_TOT / 8, 128, 0, stream>>>(feat0, feat1, W0, b0, W1, b1,
                                              Wm1, bm1, Wm2, bm2, xbuf);

    void* args[] = {
        (void*)&src, (void*)&dst, (void*)&rel,
        (void*)&xbuf, (void*)&xalt,
        (void*)&deg_i, (void*)&dinv, (void*)&rp, (void*)&fill,
        (void*)&csr_dst, (void*)&csr_w, (void*)&csr_edinv,
        (void*)&part, (void*)&poff,
        (void*)&accbuf, (void*)&ug, (void*)&c_l1, (void*)&act,
        (void*)&cur_slot
    };
    hipLaunchCooperativeKernel((const void*)coop_kernel, dim3(GRID_C), dim3(256),
                               args, 0, stream);

    final_kernel<<<N_TOT / 2, 256, 0, stream>>>(cur_slot, Wout, bout, ug, out);
}

// Round 4
// 697.753 us; speedup vs baseline: 3.4041x; 3.4041x over previous
//
#include <hip/hip_runtime.h>
#include <cmath>

typedef unsigned short ushort_t;
typedef unsigned int uint_t;

#define N_TOT 30000
#define N0_   18000
#define R_    5
#define E_    600000
#define RN    (R_ * N_TOT)
#define NC_   (N_TOT * 8)        // logits elements
#define NX_   (N_TOT * 128)      // x elements

__device__ __forceinline__ ushort_t f2bf(float f) {
    uint_t u = __float_as_uint(f);
    uint_t r = (u + 0x7fffu + ((u >> 16) & 1u)) >> 16;   // RTNE
    return (ushort_t)r;
}
__device__ __forceinline__ float bflo(uint_t v) { return __uint_as_float(v << 16); }
__device__ __forceinline__ float bfhi(uint_t v) { return __uint_as_float(v & 0xffff0000u); }

// ---------------------------------------------------------------------------
// init: u = 1/R, act[0] = 1, accbuf[0:128) = 0
// ---------------------------------------------------------------------------
__global__ void init_kernel(float* ug, int* act, float* accbuf) {
    if (threadIdx.x < 5) ug[threadIdx.x] = 0.2f;
    if (threadIdx.x == 0) act[0] = 1;
    if (threadIdx.x < 128) accbuf[threadIdx.x] = 0.0f;
}

// ---------------------------------------------------------------------------
// Fused MLP, 8 nodes per 128-thread block (R2 structure) + bf16 shadow write
// ---------------------------------------------------------------------------
__global__ __launch_bounds__(128) void mlp_kernel(
    const float* __restrict__ feat0, const float* __restrict__ feat1,
    const float* __restrict__ W0, const float* __restrict__ b0,
    const float* __restrict__ W1, const float* __restrict__ b1,
    const float* __restrict__ Wm1, const float* __restrict__ bm1,
    const float* __restrict__ Wm2, const float* __restrict__ bm2,
    float* __restrict__ xout, ushort_t* __restrict__ xh)
{
    const int j = threadIdx.x;
    const int lane = j & 63, wv_id = j >> 6;
    const int row0 = blockIdx.x * 8;

    __shared__ float sh[8][128];
    __shared__ float red[2][8];

    const bool is0 = (row0 < N0_);
    const float* __restrict__ fbase =
        is0 ? feat0 + (size_t)row0 * 256 : feat1 + (size_t)(row0 - N0_) * 128;
    const float* __restrict__ W = is0 ? W0 : W1;
    const int K = is0 ? 256 : 128;
    const float bias = is0 ? b0[j] : b1[j];

    float acc[8];
    #pragma unroll
    for (int p = 0; p < 8; ++p) acc[p] = bias;

    for (int k = 0; k < K; k += 4) {
        float w0 = W[(k + 0) * 128 + j];
        float w1 = W[(k + 1) * 128 + j];
        float w2 = W[(k + 2) * 128 + j];
        float w3 = W[(k + 3) * 128 + j];
        #pragma unroll
        for (int p = 0; p < 8; ++p) {
            const float4 f4 = *(const float4*)(fbase + (size_t)p * K + k);
            acc[p] = fmaf(f4.x, w0, acc[p]);
            acc[p] = fmaf(f4.y, w1, acc[p]);
            acc[p] = fmaf(f4.z, w2, acc[p]);
            acc[p] = fmaf(f4.w, w3, acc[p]);
        }
    }
    #pragma unroll
    for (int p = 0; p < 8; ++p) sh[p][j] = acc[p];
    __syncthreads();

    float t1[8];
    #pragma unroll
    for (int p = 0; p < 8; ++p) t1[p] = bm1[j];
    for (int k = 0; k < 128; k += 4) {
        float w0 = Wm1[(k + 0) * 128 + j];
        float w1 = Wm1[(k + 1) * 128 + j];
        float w2 = Wm1[(k + 2) * 128 + j];
        float w3 = Wm1[(k + 3) * 128 + j];
        #pragma unroll
        for (int p = 0; p < 8; ++p) {
            const float4 f4 = *(const float4*)(&sh[p][k]);
            t1[p] = fmaf(f4.x, w0, t1[p]);
            t1[p] = fmaf(f4.y, w1, t1[p]);
            t1[p] = fmaf(f4.z, w2, t1[p]);
            t1[p] = fmaf(f4.w, w3, t1[p]);
        }
    }

    float mean[8];
    {
        #pragma unroll
        for (int p = 0; p < 8; ++p) {
            float s = t1[p];
            for (int o = 32; o > 0; o >>= 1) s += __shfl_down(s, o, 64);
            if (lane == 0) red[wv_id][p] = s;
        }
        __syncthreads();
        #pragma unroll
        for (int p = 0; p < 8; ++p) mean[p] = (red[0][p] + red[1][p]) * (1.0f / 128.0f);
        __syncthreads();
        #pragma unroll
        for (int p = 0; p < 8; ++p) {
            float d = t1[p] - mean[p];
            float s = d * d;
            for (int o = 32; o > 0; o >>= 1) s += __shfl_down(s, o, 64);
            if (lane == 0) red[wv_id][p] = s;
        }
        __syncthreads();
    }
    #pragma unroll
    for (int p = 0; p < 8; ++p) {
        float var = (red[0][p] + red[1][p]) * (1.0f / 128.0f);
        float z = fmaxf((t1[p] - mean[p]) / sqrtf(var + 1e-5f), 0.0f);
        t1[p] = z;
    }
    __syncthreads();
    #pragma unroll
    for (int p = 0; p < 8; ++p) sh[p][j] = t1[p];
    __syncthreads();

    float t2[8];
    #pragma unroll
    for (int p = 0; p < 8; ++p) t2[p] = bm2[j];
    for (int k = 0; k < 128; k += 4) {
        float w0 = Wm2[(k + 0) * 128 + j];
        float w1 = Wm2[(k + 1) * 128 + j];
        float w2 = Wm2[(k + 2) * 128 + j];
        float w3 = Wm2[(k + 3) * 128 + j];
        #pragma unroll
        for (int p = 0; p < 8; ++p) {
            const float4 f4 = *(const float4*)(&sh[p][k]);
            t2[p] = fmaf(f4.x, w0, t2[p]);
            t2[p] = fmaf(f4.y, w1, t2[p]);
            t2[p] = fmaf(f4.z, w2, t2[p]);
            t2[p] = fmaf(f4.w, w3, t2[p]);
        }
    }

    float mu[8];
    {
        #pragma unroll
        for (int p = 0; p < 8; ++p) {
            float s = t2[p];
            for (int o = 32; o > 0; o >>= 1) s += __shfl_down(s, o, 64);
            if (lane == 0) red[wv_id][p] = s;
        }
        __syncthreads();
        #pragma unroll
        for (int p = 0; p < 8; ++p) mu[p] = (red[0][p] + red[1][p]) * (1.0f / 128.0f);
        __syncthreads();
        #pragma unroll
        for (int p = 0; p < 8; ++p) {
            float d = t2[p] - mu[p];
            float s = d * d;
            for (int o = 32; o > 0; o >>= 1) s += __shfl_down(s, o, 64);
            if (lane == 0) red[wv_id][p] = s;
        }
        __syncthreads();
    }
    #pragma unroll
    for (int p = 0; p < 8; ++p) {
        float sd = sqrtf((red[0][p] + red[1][p]) * (1.0f / 127.0f));
        float r = (t2[p] - mu[p]) / sd;
        if (!(fabsf(r) <= 3.402823466e38f)) {
            r = (r != r) ? 0.0f : ((r > 0.0f) ? 3.402823466e38f : -3.402823466e38f);
        }
        xout[(size_t)(row0 + p) * 128 + j] = r;
        xh[(size_t)(row0 + p) * 128 + j] = f2bf(r);
    }
}

// ---------------------------------------------------------------------------
// preprocessing
// ---------------------------------------------------------------------------
__global__ void deg_kernel(const int* __restrict__ src, const int* __restrict__ rel,
                           int* __restrict__ deg_i)
{
    int e = blockIdx.x * 256 + threadIdx.x;
    if (e >= E_) return;
    atomicAdd(&deg_i[rel[e] * N_TOT + src[e]], 1);
}

__global__ void dinv_kernel(const int* __restrict__ deg_i, float* __restrict__ dinv)
{
    int i = blockIdx.x * 256 + threadIdx.x;
    if (i >= RN) return;
    int dg = deg_i[i];
    dinv[i] = (dg > 0) ? 1.0f / sqrtf((float)dg) : 0.0f;
}

__global__ __launch_bounds__(1024) void scan_kernel(const int* __restrict__ cnt,
                                                    int* __restrict__ rp)
{
    __shared__ int wsum[16];
    __shared__ int s_carry;
    const int t = threadIdx.x, lane = t & 63, w = t >> 6;
    if (t == 0) s_carry = 0;
    __syncthreads();
    const int CH = 8192;
    for (int base = 0; base < RN; base += CH) {
        int v[8]; int s = 0;
        const int i0 = base + t * 8;
        #pragma unroll
        for (int i = 0; i < 8; ++i) { int ii = i0 + i; v[i] = (ii < RN) ? cnt[ii] : 0; s += v[i]; }
        int sc = s;
        #pragma unroll
        for (int o = 1; o < 64; o <<= 1) { int tmp = __shfl_up(sc, o, 64); if (lane >= o) sc += tmp; }
        if (lane == 63) wsum[w] = sc;
        __syncthreads();
        int woff = 0;
        for (int i = 0; i < w; ++i) woff += wsum[i];
        int run = s_carry + woff + (sc - s);
        #pragma unroll
        for (int i = 0; i < 8; ++i) { int ii = i0 + i; if (ii < RN) rp[ii] = run; run += v[i]; }
        int chunk_total = woff + sc;   // valid for t==1023
        __syncthreads();
        if (t == 1023) s_carry += chunk_total;
        __syncthreads();
    }
    if (threadIdx.x == 0) rp[RN] = s_carry;
}

__global__ void scatter_kernel(const int* __restrict__ src, const int* __restrict__ dst,
                               const int* __restrict__ rel, const int* __restrict__ rp,
                               int* __restrict__ fill, const int* __restrict__ deg_i,
                               const float* __restrict__ dinv,
                               int* __restrict__ csr_dst, float* __restrict__ csr_w,
                               float* __restrict__ csr_edinv)
{
    int e = blockIdx.x * 256 + threadIdx.x;
    if (e >= E_) return;
    int s = src[e], r = rel[e], d = dst[e];
    int key = r * N_TOT + s;
    int pos = rp[key] + atomicAdd(&fill[key], 1);
    csr_dst[pos] = d;
    csr_w[pos] = 1.0f / (float)deg_i[key];
    csr_edinv[pos] = dinv[key] * dinv[r * N_TOT + d];
}

// ---------------------------------------------------------------------------
// tv: bf16 gathers (4 B/lane), edge loop unrolled x2, accumulate into
// accbuf[k*16 + {0..4 node, 5..9 edge}] (pre-zeroed in init).
// ---------------------------------------------------------------------------
__global__ __launch_bounds__(256) void tv_kernel(
    const ushort_t* __restrict__ xh, const int* __restrict__ rp,
    const int* __restrict__ csr_dst, const float* __restrict__ csr_edinv,
    const int* __restrict__ act, int k, float* __restrict__ accbuf)
{
    if (act[k] == 0) return;
    const int lane = threadIdx.x & 63;
    const int wv = threadIdx.x >> 6;
    const int wid = blockIdx.x * 4 + wv;
    const int nw = gridDim.x * 4;
    float na[5] = {0, 0, 0, 0, 0};
    float ea[5] = {0, 0, 0, 0, 0};
    for (int n = wid; n < N_TOT; n += nw) {
        const uint_t vs = ((const uint_t*)(xh + (size_t)n * 128))[lane];
        const float sx = bflo(vs), sy = bfhi(vs);
        const float pp = fmaf(sx, sx, sy * sy);
        #pragma unroll
        for (int r = 0; r < 5; ++r) {
            const int e0 = rp[r * N_TOT + n];
            const int e1 = rp[r * N_TOT + n + 1];
            if (e1 > e0) na[r] += pp;
            float acc0 = 0.0f, acc1 = 0.0f;
            int e = e0;
            for (; e + 2 <= e1; e += 2) {
                const int dn0 = csr_dst[e];
                const int dn1 = csr_dst[e + 1];
                const float w0 = csr_edinv[e];
                const float w1 = csr_edinv[e + 1];
                const uint_t v0 = ((const uint_t*)(xh + (size_t)dn0 * 128))[lane];
                const uint_t v1 = ((const uint_t*)(xh + (size_t)dn1 * 128))[lane];
                acc0 = fmaf(w0, fmaf(sx, bflo(v0), sy * bfhi(v0)), acc0);
                acc1 = fmaf(w1, fmaf(sx, bflo(v1), sy * bfhi(v1)), acc1);
            }
            if (e < e1) {
                const int dn0 = csr_dst[e];
                const float w0 = csr_edinv[e];
                const uint_t v0 = ((const uint_t*)(xh + (size_t)dn0 * 128))[lane];
                acc0 = fmaf(w0, fmaf(sx, bflo(v0), sy * bfhi(v0)), acc0);
            }
            ea[r] += acc0 + acc1;
        }
    }
    __shared__ float sacc[4][10];
    #pragma unroll
    for (int r = 0; r < 5; ++r) {
        float a = na[r], b2 = ea[r];
        for (int o = 32; o > 0; o >>= 1) {
            a += __shfl_down(a, o, 64);
            b2 += __shfl_down(b2, o, 64);
        }
        if (lane == 0) { sacc[wv][r] = a; sacc[wv][5 + r] = b2; }
    }
    __syncthreads();
    if (threadIdx.x < 10) {
        float t = sacc[0][threadIdx.x] + sacc[1][threadIdx.x] +
                  sacc[2][threadIdx.x] + sacc[3][threadIdx.x];
        atomicAdd(&accbuf[k * 16 + threadIdx.x], t);
    }
}

// ---------------------------------------------------------------------------
// scalar: fp32 lane-parallel mirror descent (lanes 0..7 of one wave)
// ---------------------------------------------------------------------------
__global__ void scalar_kernel(const float* __restrict__ accbuf, float* __restrict__ ug,
                              float* __restrict__ c_l1, int* __restrict__ act, int k)
{
    if (blockIdx.x != 0 || threadIdx.x >= 8) return;
    const int r = threadIdx.x;
    const int a = act[k];
    float w = (r < 5) ? (accbuf[k * 16 + r] - accbuf[k * 16 + 5 + r]) * (1.0f / 30000.0f)
                      : 0.0f;
    float l1 = fabsf(w);
    for (int o = 4; o > 0; o >>= 1) l1 += __shfl_xor(l1, o, 8);
    if (k == 0 && r == 0) c_l1[0] = l1;
    if (!a) { if (r == 0) act[k + 1] = 0; return; }
    float u = (r < 5) ? ug[r] : 0.0f;
    const float fi = l1 + 3.0f;
    bool mact = true;
    for (int t = 1; t <= 20; ++t) {
        float T = sqrtf(3.2188758248682006f / ((float)t * fi * fi));
        float ta = u * expf(-T * (3.0f * u + w));
        float ssum = ta;
        for (int o = 4; o > 0; o >>= 1) ssum += __shfl_xor(ssum, o, 8);
        float un = ta / ssum;
        float d0 = u - un;
        float dq = d0 * d0;
        for (int o = 4; o > 0; o >>= 1) dq += __shfl_xor(dq, o, 8);
        if (mact) u = un;
        mact = mact && (sqrtf(dq) >= 1e-3f);
    }
    if (r < 5) ug[r] = u;
    if (r == 0) act[k + 1] = (l1 / c_l1[0] >= 0.3f) ? 1 : 0;
}

// ---------------------------------------------------------------------------
// msg + update: bf16 gathers, fp32 x updated IN PLACE, bf16 shadow ping-pong.
// ---------------------------------------------------------------------------
__global__ __launch_bounds__(256) void msg_upd_kernel(
    float* __restrict__ x, const ushort_t* __restrict__ xh_in,
    ushort_t* __restrict__ xh_out,
    const int* __restrict__ rp, const int* __restrict__ csr_dst,
    const float* __restrict__ csr_w, const float* __restrict__ ug,
    const int* __restrict__ act, int k)
{
    if (act[k + 1] == 0) return;
    const int lane = threadIdx.x & 63;
    const int wid = blockIdx.x * 4 + (threadIdx.x >> 6);
    const int nw = gridDim.x * 4;
    const float u0 = ug[0], u1 = ug[1], u2 = ug[2], u3 = ug[3], u4 = ug[4];
    for (int n = wid; n < N_TOT; n += nw) {
        float ax0 = 0.0f, ay0 = 0.0f, ax1 = 0.0f, ay1 = 0.0f;
        #pragma unroll
        for (int r = 0; r < 5; ++r) {
            const float ur = (r == 0) ? u0 : (r == 1) ? u1 : (r == 2) ? u2 : (r == 3) ? u3 : u4;
            const int e0 = rp[r * N_TOT + n];
            const int e1 = rp[r * N_TOT + n + 1];
            int e = e0;
            for (; e + 2 <= e1; e += 2) {
                const float w0 = ur * csr_w[e];
                const float w1 = ur * csr_w[e + 1];
                const int dn0 = csr_dst[e];
                const int dn1 = csr_dst[e + 1];
                const uint_t v0 = ((const uint_t*)(xh_in + (size_t)dn0 * 128))[lane];
                const uint_t v1 = ((const uint_t*)(xh_in + (size_t)dn1 * 128))[lane];
                ax0 = fmaf(w0, bflo(v0), ax0);
                ay0 = fmaf(w0, bfhi(v0), ay0);
                ax1 = fmaf(w1, bflo(v1), ax1);
                ay1 = fmaf(w1, bfhi(v1), ay1);
            }
            if (e < e1) {
                const float w0 = ur * csr_w[e];
                const int dn0 = csr_dst[e];
                const uint_t v0 = ((const uint_t*)(xh_in + (size_t)dn0 * 128))[lane];
                ax0 = fmaf(w0, bflo(v0), ax0);
                ay0 = fmaf(w0, bfhi(v0), ay0);
            }
        }
        const float ci = 1.0f / 21.0f, cb = 20.0f / 21.0f;
        float2* xp = (float2*)(x + (size_t)n * 128);
        const float2 xs = xp[lane];
        const float nx_ = fmaf(cb, ax0 + ax1, xs.x * ci);
        const float ny_ = fmaf(cb, ay0 + ay1, xs.y * ci);
        xp[lane] = make_float2(nx_, ny_);
        ((uint_t*)(xh_out + (size_t)n * 128))[lane] =
            ((uint_t)f2bf(ny_) << 16) | (uint_t)f2bf(nx_);
    }
}

// ---------------------------------------------------------------------------
// epilogue: logits = x@Wout + bout ; write logits, x, u
// ---------------------------------------------------------------------------
__global__ __launch_bounds__(256) void final_kernel(const float* __restrict__ x,
                                                    const float* __restrict__ Wout,
                                                    const float* __restrict__ bout,
                                                    const float* __restrict__ ug,
                                                    float* __restrict__ out)
{
    const int nl = threadIdx.x >> 7;
    const int n = blockIdx.x * 2 + nl;
    const int j = threadIdx.x & 127;
    const int lane = threadIdx.x & 63;
    const int wv = threadIdx.x >> 6;
    float xv = x[(size_t)n * 128 + j];
    out[(size_t)NC_ + (size_t)n * 128 + j] = xv;
    float p[8];
    #pragma unroll
    for (int c = 0; c < 8; ++c) p[c] = xv * Wout[j * 8 + c];
    #pragma unroll
    for (int c = 0; c < 8; ++c)
        for (int o = 32; o > 0; o >>= 1) p[c] += __shfl_down(p[c], o, 64);
    __shared__ float sp[4][8];
    if (lane == 0) {
        #pragma unroll
        for (int c = 0; c < 8; ++c) sp[wv][c] = p[c];
    }
    __syncthreads();
    if (j < 8) {
        int c = j;
        out[(size_t)n * 8 + c] = bout[c] + sp[2 * nl][c] + sp[2 * nl + 1][c];
    }
    if (blockIdx.x == 0 && threadIdx.x < 5)
        out[(size_t)NC_ + (size_t)NX_ + threadIdx.x] = ug[threadIdx.x];
}

// ---------------------------------------------------------------------------
extern "C" void kernel_launch(void* const* d_in, const int* in_sizes, int n_in,
                              void* d_out, int out_size, void* d_ws, size_t ws_size,
                              hipStream_t stream)
{
    const float* feat0 = (const float*)d_in[0];
    const float* feat1 = (const float*)d_in[1];
    const float* W0   = (const float*)d_in[2];
    const float* b0   = (const float*)d_in[3];
    const float* W1   = (const float*)d_in[4];
    const float* b1   = (const float*)d_in[5];
    const float* Wm1  = (const float*)d_in[6];
    const float* bm1  = (const float*)d_in[7];
    const float* Wm2  = (const float*)d_in[8];
    const float* bm2  = (const float*)d_in[9];
    const float* Wout = (const float*)d_in[10];
    const float* bout = (const float*)d_in[11];
    const int* src = (const int*)d_in[12];
    const int* dst = (const int*)d_in[13];
    const int* rel = (const int*)d_in[14];
    float* out = (float*)d_out;

    char* p = (char*)d_ws;
    auto alloc = [&](size_t bytes) { char* q = p; p += (bytes + 255) & ~(size_t)255; return q; };
    float*    xbuf      = (float*)   alloc((size_t)NX_ * 4);
    ushort_t* xh0       = (ushort_t*)alloc((size_t)NX_ * 2);
    ushort_t* xh1       = (ushort_t*)alloc((size_t)NX_ * 2);
    int*      deg_i     = (int*)     alloc((size_t)RN * 4);
    float*    dinv      = (float*)   alloc((size_t)RN * 4);
    int*      rp        = (int*)     alloc(((size_t)RN + 1) * 4);
    int*      fill      = (int*)     alloc((size_t)RN * 4);
    int*      csr_dst   = (int*)     alloc((size_t)E_ * 4);
    float*    csr_w     = (float*)   alloc((size_t)E_ * 4);
    float*    csr_edinv = (float*)   alloc((size_t)E_ * 4);
    float*    accbuf    = (float*)   alloc(128 * 4);
    float*    ug        = (float*)   alloc(64);
    float*    c_l1      = (float*)   alloc(64);
    int*      act       = (int*)     alloc(64);

    hipMemsetAsync(deg_i, 0, (size_t)RN * 4, stream);
    hipMemsetAsync(fill, 0, (size_t)RN * 4, stream);
    init_kernel<<<1, 128, 0, stream>>>(ug, act, accbuf);

    mlp_kernel<<<N_TOT / 8, 128, 0, stream>>>(feat0, feat1, W0, b0, W1, b1,
                                              Wm1, bm1, Wm2, bm2, xbuf, xh0);

    deg_kernel<<<(E_ + 255) / 256, 256, 0, stream>>>(src, rel, deg_i);
    dinv_kernel<<<(RN + 255) / 256, 256, 0, stream>>>(deg_i, dinv);
    scan_kernel<<<1, 1024, 0, stream>>>(deg_i, rp);
    scatter_kernel<<<(E_ + 255) / 256, 256, 0, stream>>>(src, dst, rel, rp, fill,
                                                         deg_i, dinv,
                                                         csr_dst, csr_w, csr_edinv);

    ushort_t* ha = xh0;
    ushort_t* hb = xh1;
    for (int k = 0; k < 8; ++k) {
        tv_kernel<<<2048, 256, 0, stream>>>(ha, rp, csr_dst, csr_edinv, act, k, accbuf);
        scalar_kernel<<<1, 64, 0, stream>>>(accbuf, ug, c_l1, act, k);
        msg_upd_kernel<<<2048, 256, 0, stream>>>(xbuf, ha, hb, rp, csr_dst, csr_w,
                                                 ug, act, k);
        ushort_t* t = ha; ha = hb; hb = t;
    }

    final_kernel<<<N_TOT / 2, 256, 0, stream>>>(xbuf, Wout, bout, ug, out);
}